// Round 2
// baseline (389.352 us; speedup 1.0000x reference)
//
#include <hip/hip_runtime.h>
#include <math.h>

#define BIGV 10000.0f

constexpr int B = 32, S = 4096, D = 512;
constexpr int C   = 32;           // chunks (blocks) per batch
constexpr int L   = S / C;        // 128 rows per chunk
constexpr int WPB = 4;            // waves per block (256 threads)
constexpr int RW  = L / WPB;      // 32 rows per wave
constexpr int NREC = B * C * WPB; // 4096 wave records
constexpr int RPB  = C * WPB;     // 128 records per batch

// ------------- kernel 1: barrier-free streaming partials -------------------
__global__ __launch_bounds__(256, 4)
void pool_stream(const float* __restrict__ x, const int* __restrict__ mask,
                 const float* __restrict__ wvec, float* __restrict__ ws) {
  const int tid = threadIdx.x, lane = tid & 63, w = tid >> 6;
  const int blk = blockIdx.x, b = blk / C, c = blk % C;
  const int s0 = c * L + w * RW;                   // this wave's first row

  const float4* xrow4 = (const float4*)(x + ((size_t)b * S + s0) * D);
  const int*    mr    = mask + (size_t)b * S + s0;

  const float4* wv4 = (const float4*)wvec;
  const float4  w0 = wv4[lane * 2], w1 = wv4[lane * 2 + 1];

  float m = -INFINITY, l = 0.f, cnt = 0.f;
  float o[8], sm[8], mx[8], mn[8];
  #pragma unroll
  for (int j = 0; j < 8; ++j) { o[j] = 0.f; sm[j] = 0.f; mx[j] = -BIGV; mn[j] = BIGV; }

  // prime the 1-row register pipeline
  float4 a0 = xrow4[lane * 2];
  float4 a1 = xrow4[lane * 2 + 1];
  int    mb = mr[0];

  for (int r = 0; r < RW; ++r) {
    const float4 c0 = a0, c1 = a1; const int cm = mb;
    if (r + 1 < RW) {                              // prefetch next row (uniform branch)
      a0 = xrow4[(size_t)(r + 1) * (D / 4) + lane * 2];
      a1 = xrow4[(size_t)(r + 1) * (D / 4) + lane * 2 + 1];
      mb = mr[r + 1];
    }
    // dot partial over this lane's 8 columns
    float d = 0.f;
    d = fmaf(c0.x, w0.x, d); d = fmaf(c0.y, w0.y, d);
    d = fmaf(c0.z, w0.z, d); d = fmaf(c0.w, w0.w, d);
    d = fmaf(c1.x, w1.x, d); d = fmaf(c1.y, w1.y, d);
    d = fmaf(c1.z, w1.z, d); d = fmaf(c1.w, w1.w, d);
    // butterfly: all 64 lanes end with the full row dot
    #pragma unroll
    for (int off = 32; off; off >>= 1) d += __shfl_xor(d, off, 64);

    const float s = cm ? d : -BIGV;
    const float m_new = fmaxf(m, s);
    if (m_new > m) {                               // wave-uniform, rare after warm-up
      const float alpha = __expf(m - m_new);       // exp(-inf)=0 on first row
      l *= alpha;
      #pragma unroll
      for (int j = 0; j < 8; ++j) o[j] *= alpha;
      m = m_new;
    }
    const float p = __expf(s - m);                 // masked rows: exp(-1e4-m) == 0
    l += p;
    const float mskf = cm ? 1.f : 0.f;
    cnt += mskf;

    const float xa[8] = {c0.x, c0.y, c0.z, c0.w, c1.x, c1.y, c1.z, c1.w};
    #pragma unroll
    for (int j = 0; j < 8; ++j) {
      o[j]  = fmaf(p, xa[j], o[j]);
      sm[j] = fmaf(mskf, xa[j], sm[j]);
      mx[j] = fmaxf(mx[j], cm ? xa[j] : -BIGV);
      mn[j] = fminf(mn[j], cm ? xa[j] :  BIGV);
    }
  }

  // ---- write this wave's record (coalesced float4 stores) ----
  const size_t rec = (size_t)blk * WPB + w;
  float4* po = (float4*)(ws + rec * D);
  float4* ps = (float4*)(ws + (size_t)NREC * D + rec * D);
  float4* px = (float4*)(ws + 2 * (size_t)NREC * D + rec * D);
  float4* pn = (float4*)(ws + 3 * (size_t)NREC * D + rec * D);
  po[lane * 2]     = make_float4(o[0], o[1], o[2], o[3]);
  po[lane * 2 + 1] = make_float4(o[4], o[5], o[6], o[7]);
  ps[lane * 2]     = make_float4(sm[0], sm[1], sm[2], sm[3]);
  ps[lane * 2 + 1] = make_float4(sm[4], sm[5], sm[6], sm[7]);
  px[lane * 2]     = make_float4(mx[0], mx[1], mx[2], mx[3]);
  px[lane * 2 + 1] = make_float4(mx[4], mx[5], mx[6], mx[7]);
  pn[lane * 2]     = make_float4(mn[0], mn[1], mn[2], mn[3]);
  pn[lane * 2 + 1] = make_float4(mn[4], mn[5], mn[6], mn[7]);
  if (lane == 0) {
    float* scal = ws + 4 * (size_t)NREC * D;
    scal[rec]            = m;
    scal[NREC + rec]     = l;
    scal[2 * NREC + rec] = cnt;
  }
}

// ------------- kernel 2: flash-merge 128 records per batch -----------------
__global__ __launch_bounds__(512)
void pool_merge(const float* __restrict__ ws, float* __restrict__ out) {
  const int b = blockIdx.x, tid = threadIdx.x;
  const float* scal = ws + 4 * (size_t)NREC * D;
  const int r0 = b * RPB;

  float m_f = -INFINITY;
  #pragma unroll 4
  for (int i = 0; i < RPB; ++i) m_f = fmaxf(m_f, scal[r0 + i]);

  float Lsum = 0.f, CNT = 0.f;
  float o = 0.f, sm = 0.f, mx = -BIGV, mn = BIGV;
  #pragma unroll 4
  for (int i = 0; i < RPB; ++i) {
    const size_t rec = (size_t)(r0 + i);
    const float a = __expf(scal[rec] - m_f);
    Lsum += scal[NREC + rec] * a;
    CNT  += scal[2 * NREC + rec];
    o  = fmaf(ws[rec * D + tid], a, o);
    sm += ws[(size_t)NREC * D + rec * D + tid];
    mx  = fmaxf(mx, ws[2 * (size_t)NREC * D + rec * D + tid]);
    mn  = fminf(mn, ws[3 * (size_t)NREC * D + rec * D + tid]);
  }
  float* ob = out + (size_t)b * 4 * D;
  ob[tid]         = sm / (CNT + 1e-6f);
  ob[D + tid]     = mx;
  ob[2 * D + tid] = mn;
  ob[3 * D + tid] = o / Lsum;
}

extern "C" void kernel_launch(void* const* d_in, const int* in_sizes, int n_in,
                              void* d_out, int out_size, void* d_ws, size_t ws_size,
                              hipStream_t stream) {
  const float* x    = (const float*)d_in[0];
  const int*   mask = (const int*)d_in[1];
  const float* w    = (const float*)d_in[2];
  float* out = (float*)d_out;
  float* ws  = (float*)d_ws;

  pool_stream<<<dim3(B * C), dim3(256), 0, stream>>>(x, mask, w, ws);
  pool_merge<<<dim3(B), dim3(512), 0, stream>>>(ws, out);
}

// Round 3
// 365.263 us; speedup vs baseline: 1.0660x; 1.0660x over previous
//
#include <hip/hip_runtime.h>
#include <math.h>

#define BIGV 10000.0f

constexpr int B = 32, S = 4096, D = 512;
constexpr int C    = 32;          // blocks per batch
constexpr int L    = S / C;       // 128 rows per block
constexpr int WPB  = 4;           // waves per block (256 threads)
constexpr int RW   = L / WPB;     // 32 rows per wave
constexpr int NREC = B * C;       // 1024 block records
constexpr int RPB  = C;           // 32 records per batch

// ------------- kernel 1: barrier-free streaming + one LDS block-merge ------
__global__ __launch_bounds__(256, 4)
void pool_stream(const float* __restrict__ x, const int* __restrict__ mask,
                 const float* __restrict__ wvec, float* __restrict__ ws) {
  __shared__ float ls_o[WPB][D];   // 8 KB each, 32 KB total
  __shared__ float ls_sm[WPB][D];
  __shared__ float ls_mx[WPB][D];
  __shared__ float ls_mn[WPB][D];
  __shared__ float ls_m[WPB], ls_l[WPB], ls_c[WPB];

  const int tid = threadIdx.x, lane = tid & 63, w = tid >> 6;
  const int blk = blockIdx.x, b = blk / C, c = blk % C;
  const int s0 = c * L + w * RW;                   // this wave's first row

  const float4* row4 = (const float4*)(x + ((size_t)b * S + s0) * D);
  const int*    mr   = mask + (size_t)b * S + s0;

  // contiguous lane mapping: quad A = cols 4*lane.., quad B = cols 256+4*lane..
  const float4* wv4 = (const float4*)wvec;
  const float4  w0 = wv4[lane], w1 = wv4[64 + lane];

  float m = -INFINITY, l = 0.f, cnt = 0.f;
  float o[8], sm[8], mx[8], mn[8];
  #pragma unroll
  for (int j = 0; j < 8; ++j) { o[j] = 0.f; sm[j] = 0.f; mx[j] = -BIGV; mn[j] = BIGV; }

  // 2-row register pipeline
  float4 cur0 = row4[lane],       cur1 = row4[64 + lane];        int curm = mr[0];
  float4 nx0  = row4[128 + lane], nx1  = row4[192 + lane];       int nxm  = mr[1];

  for (int r = 0; r < RW; ++r) {
    const float4 c0 = cur0, c1 = cur1; const int cm = curm;
    cur0 = nx0; cur1 = nx1; curm = nxm;
    if (r + 2 < RW) {
      nx0 = row4[(size_t)(r + 2) * (D / 4) + lane];
      nx1 = row4[(size_t)(r + 2) * (D / 4) + 64 + lane];
      nxm = mr[r + 2];
    }

    float d = 0.f;
    d = fmaf(c0.x, w0.x, d); d = fmaf(c0.y, w0.y, d);
    d = fmaf(c0.z, w0.z, d); d = fmaf(c0.w, w0.w, d);
    d = fmaf(c1.x, w1.x, d); d = fmaf(c1.y, w1.y, d);
    d = fmaf(c1.z, w1.z, d); d = fmaf(c1.w, w1.w, d);
    #pragma unroll
    for (int off = 32; off; off >>= 1) d += __shfl_xor(d, off, 64);

    const float s = cm ? d : -BIGV;
    const float m_new = fmaxf(m, s);
    if (m_new > m) {                               // wave-uniform branch
      const float alpha = __expf(m - m_new);       // exp(-inf)=0 on first row
      l *= alpha;
      #pragma unroll
      for (int j = 0; j < 8; ++j) o[j] *= alpha;
      m = m_new;
    }
    const float p = __expf(s - m);                 // masked: exp(-1e4-m) -> 0
    l += p;
    const float mskf = cm ? 1.f : 0.f;
    cnt += mskf;

    const float xa[8] = {c0.x, c0.y, c0.z, c0.w, c1.x, c1.y, c1.z, c1.w};
    #pragma unroll
    for (int j = 0; j < 8; ++j) {
      o[j]  = fmaf(p, xa[j], o[j]);
      sm[j] = fmaf(mskf, xa[j], sm[j]);
      mx[j] = fmaxf(mx[j], cm ? xa[j] : -BIGV);
      mn[j] = fminf(mn[j], cm ? xa[j] :  BIGV);
    }
  }

  // ---- intra-block merge: 4 wave records -> 1 block record ----
  ((float4*)ls_o[w])[lane]       = make_float4(o[0], o[1], o[2], o[3]);
  ((float4*)ls_o[w])[64 + lane]  = make_float4(o[4], o[5], o[6], o[7]);
  ((float4*)ls_sm[w])[lane]      = make_float4(sm[0], sm[1], sm[2], sm[3]);
  ((float4*)ls_sm[w])[64 + lane] = make_float4(sm[4], sm[5], sm[6], sm[7]);
  ((float4*)ls_mx[w])[lane]      = make_float4(mx[0], mx[1], mx[2], mx[3]);
  ((float4*)ls_mx[w])[64 + lane] = make_float4(mx[4], mx[5], mx[6], mx[7]);
  ((float4*)ls_mn[w])[lane]      = make_float4(mn[0], mn[1], mn[2], mn[3]);
  ((float4*)ls_mn[w])[64 + lane] = make_float4(mn[4], mn[5], mn[6], mn[7]);
  if (lane == 0) { ls_m[w] = m; ls_l[w] = l; ls_c[w] = cnt; }
  __syncthreads();

  float m_blk = fmaxf(fmaxf(ls_m[0], ls_m[1]), fmaxf(ls_m[2], ls_m[3]));
  float al[WPB];
  float l_f = 0.f, c_f = 0.f;
  #pragma unroll
  for (int k = 0; k < WPB; ++k) {
    al[k] = __expf(ls_m[k] - m_blk);
    l_f += ls_l[k] * al[k];
    c_f += ls_c[k];
  }
  // thread owns columns tid and 256+tid
  #pragma unroll
  for (int h = 0; h < 2; ++h) {
    const int col = h * 256 + tid;
    float of = 0.f, sf = 0.f, xf = -BIGV, nf = BIGV;
    #pragma unroll
    for (int k = 0; k < WPB; ++k) {
      of = fmaf(ls_o[k][col], al[k], of);
      sf += ls_sm[k][col];
      xf  = fmaxf(xf, ls_mx[k][col]);
      nf  = fminf(nf, ls_mn[k][col]);
    }
    const size_t rec = (size_t)blk;
    ws[rec * D + col]                      = of;
    ws[(size_t)NREC * D + rec * D + col]   = sf;
    ws[2 * (size_t)NREC * D + rec * D + col] = xf;
    ws[3 * (size_t)NREC * D + rec * D + col] = nf;
  }
  if (tid == 0) {
    float* scal = ws + 4 * (size_t)NREC * D;
    scal[blk]            = m_blk;
    scal[NREC + blk]     = l_f;
    scal[2 * NREC + blk] = c_f;
  }
}

// ------------- kernel 2: flash-merge 32 records per batch ------------------
__global__ __launch_bounds__(128)
void pool_merge(const float* __restrict__ ws, float* __restrict__ out) {
  const int b = blockIdx.x, q = blockIdx.y, tid = threadIdx.x;
  const int col = q * 128 + tid;
  const float* scal = ws + 4 * (size_t)NREC * D;
  const int r0 = b * RPB;

  float m_f = -INFINITY;
  #pragma unroll 8
  for (int i = 0; i < RPB; ++i) m_f = fmaxf(m_f, scal[r0 + i]);

  float Lsum = 0.f, CNT = 0.f;
  float o = 0.f, sm = 0.f, mx = -BIGV, mn = BIGV;
  #pragma unroll 4
  for (int i = 0; i < RPB; ++i) {
    const size_t rec = (size_t)(r0 + i);
    const float a = __expf(scal[rec] - m_f);
    Lsum += scal[NREC + rec] * a;
    CNT  += scal[2 * NREC + rec];
    o  = fmaf(ws[rec * D + col], a, o);
    sm += ws[(size_t)NREC * D + rec * D + col];
    mx  = fmaxf(mx, ws[2 * (size_t)NREC * D + rec * D + col]);
    mn  = fminf(mn, ws[3 * (size_t)NREC * D + rec * D + col]);
  }
  float* ob = out + (size_t)b * 4 * D;
  ob[col]         = sm / (CNT + 1e-6f);
  ob[D + col]     = mx;
  ob[2 * D + col] = mn;
  ob[3 * D + col] = o / Lsum;
}

extern "C" void kernel_launch(void* const* d_in, const int* in_sizes, int n_in,
                              void* d_out, int out_size, void* d_ws, size_t ws_size,
                              hipStream_t stream) {
  const float* x    = (const float*)d_in[0];
  const int*   mask = (const int*)d_in[1];
  const float* w    = (const float*)d_in[2];
  float* out = (float*)d_out;
  float* ws  = (float*)d_ws;

  pool_stream<<<dim3(B * C), dim3(256), 0, stream>>>(x, mask, w, ws);
  pool_merge<<<dim3(B, 4), dim3(128), 0, stream>>>(ws, out);
}